// Round 1
// 83.678 us; speedup vs baseline: 1.1595x; 1.1595x over previous
//
#include <hip/hip_runtime.h>

// SSIM map — fused 3-stage tile kernel, round-2: 32x64 tile / 512 threads.
// B=16, C=3, H=W=512, 11-tap separable gaussian (sigma=1.5).
//
// Per 512-thread block: 32x64 output tile (was 32x32/256t).
//   Stage 1: global -> LDS float2(x,y), 42x74 halo tile, zero-padded.
//   Stage 2: horizontal 11-tap conv; each thread computes 4 CONSECUTIVE cols
//            from 14 register-cached taps. 592 items over 512 threads.
//   Stage 3: vertical 11-tap conv; each thread computes 4 CONSECUTIVE rows
//            (16 row-groups x 32 cols = 512 threads), SSIM epilogue,
//            coalesced store.
// Rationale vs round-1: LDS 42.5KB/256t gave 3 blk/CU = 12 waves/CU (32.5%
// measured occupancy) with VALUBusy only 48.5% -> latency/overlap bound.
// 32x64 tile: 74.3KB LDS -> 2 blk/CU x 8 waves = 16 waves/CU (50%), and
// halo factor 1.72 -> 1.52 (12% less h-conv work + HBM fetch).
// Exactly 2 __syncthreads per block lifetime. Bank-spread pitches kept
// (sbuf pitch 43 float2; hf pitch 33).

#define W    512
#define H    512
#define BC   48
#define TX   32
#define TY   64
#define IX   42          // TX + 10
#define IY   74          // TY + 10
#define SP   43          // sbuf float2 pitch
#define HP   33          // hf pitch
#define NT   512

__global__ __launch_bounds__(NT) void ssim_kernel(
    const float* __restrict__ x, const float* __restrict__ y,
    float* __restrict__ out)
{
    __shared__ float2 sbuf[IY][SP];   // 25456 B: raw (x,y), halo tile
    __shared__ float4 hf4[IY][HP];    // 39072 B: h-conv (x,y,xx,yy)
    __shared__ float  hfx[IY][HP];    //  9768 B: h-conv (xy)
                                      // total 74296 B -> 2 blocks/CU

    // fp32-normalized gaussian, sigma=1.5, K=11 (matches np reference ~1e-7)
    const float g[11] = {
        0.00102838f, 0.00759875f, 0.03600077f, 0.10936069f, 0.21300553f,
        0.26601172f,
        0.21300553f, 0.10936069f, 0.03600077f, 0.00759875f, 0.00102838f};

    const int tid = threadIdx.x;
    const int bc  = blockIdx.z;
    const int c0  = blockIdx.x * TX;
    const int r0  = blockIdx.y * TY;

    const float* __restrict__ xp = x + (size_t)bc * H * W;
    const float* __restrict__ yp = y + (size_t)bc * H * W;

    // ---- Stage 1: global -> LDS, zero-padded halo tile (74x42 = 3108) ----
#pragma unroll
    for (int it = 0; it < 7; ++it) {
        const int idx = tid + it * NT;
        if (idx < IY * IX) {
            const int r  = idx / IX;
            const int c  = idx - r * IX;
            const int gr = r0 - 5 + r;
            const int gc = c0 - 5 + c;
            float vx = 0.f, vy = 0.f;
            if ((unsigned)gr < (unsigned)H && (unsigned)gc < (unsigned)W) {
                const size_t gi = (size_t)gr * W + gc;
                vx = xp[gi];
                vy = yp[gi];
            }
            sbuf[r][c] = make_float2(vx, vy);
        }
    }
    __syncthreads();

    // ---- Stage 2: horizontal conv, 4 consecutive cols per thread ----
    // item = row * 8 + colgroup; 74 rows x 8 groups = 592 items
#pragma unroll
    for (int it = 0; it < 2; ++it) {
        const int item = tid + it * NT;
        if (item < IY * 8) {
            const int row = item >> 3;
            const int cb  = (item & 7) << 2;     // base output col 0..28

            float2 v[14];
#pragma unroll
            for (int kk = 0; kk < 14; ++kk) v[kk] = sbuf[row][cb + kk];

            float a[4][5];
#pragma unroll
            for (int kk = 0; kk < 14; ++kk) {
                const float px  = v[kk].x, py = v[kk].y;
                const float pxx = px * px;
                const float pyy = py * py;
                const float pxy = px * py;
#pragma unroll
                for (int j = 0; j < 4; ++j) {
                    const int m = kk - j;        // tap index for output j
                    if (m >= 0 && m <= 10) {
                        const float w = g[m];
                        if (kk == j) {           // first tap: assign
                            a[j][0] = w * px;  a[j][1] = w * py;
                            a[j][2] = w * pxx; a[j][3] = w * pyy;
                            a[j][4] = w * pxy;
                        } else {
                            a[j][0] += w * px;  a[j][1] += w * py;
                            a[j][2] += w * pxx; a[j][3] += w * pyy;
                            a[j][4] += w * pxy;
                        }
                    }
                }
            }
#pragma unroll
            for (int j = 0; j < 4; ++j) {
                hf4[row][cb + j] = make_float4(a[j][0], a[j][1], a[j][2], a[j][3]);
                hfx[row][cb + j] = a[j][4];
            }
        }
    }
    __syncthreads();

    // ---- Stage 3: vertical conv + SSIM, 4 consecutive rows per thread ----
    {
        const int tx    = tid & 31;
        const int obase = (tid >> 5) << 2;       // first output row 0,4,..,60

        float acc[4][5];
#pragma unroll
        for (int rr = 0; rr < 14; ++rr) {
            const float4 h4 = hf4[obase + rr][tx];
            const float  h5 = hfx[obase + rr][tx];
#pragma unroll
            for (int j = 0; j < 4; ++j) {
                const int m = rr - j;            // tap index for output j
                if (m >= 0 && m <= 10) {
                    const float w = g[m];
                    if (rr == j) {
                        acc[j][0] = w * h4.x; acc[j][1] = w * h4.y;
                        acc[j][2] = w * h4.z; acc[j][3] = w * h4.w;
                        acc[j][4] = w * h5;
                    } else {
                        acc[j][0] += w * h4.x; acc[j][1] += w * h4.y;
                        acc[j][2] += w * h4.z; acc[j][3] += w * h4.w;
                        acc[j][4] += w * h5;
                    }
                }
            }
        }

        float* __restrict__ op = out + (size_t)bc * H * W;
#pragma unroll
        for (int j = 0; j < 4; ++j) {
            const float mu1   = acc[j][0];
            const float mu2   = acc[j][1];
            const float mu1sq = mu1 * mu1;
            const float mu2sq = mu2 * mu2;
            const float mu12  = mu1 * mu2;
            const float s1    = acc[j][2] - mu1sq;
            const float s2    = acc[j][3] - mu2sq;
            const float s12   = acc[j][4] - mu12;
            const float num = (2.f * mu12 + 1e-4f) * (2.f * s12 + 9e-4f);
            const float den = (mu1sq + mu2sq + 1e-4f) * (s1 + s2 + 9e-4f);
            op[(size_t)(r0 + obase + j) * W + c0 + tx] =
                num * __builtin_amdgcn_rcpf(den);
        }
    }
}

extern "C" void kernel_launch(void* const* d_in, const int* in_sizes, int n_in,
                              void* d_out, int out_size, void* d_ws, size_t ws_size,
                              hipStream_t stream) {
    const float* img_out    = (const float*)d_in[0];
    const float* img_target = (const float*)d_in[1];
    // d_in[2] is window_size==11; fixed by the problem, baked into the kernel.
    float* out = (float*)d_out;

    dim3 grid(W / TX, H / TY, BC);   // 16 x 8 x 48 = 6144 blocks
    ssim_kernel<<<grid, NT, 0, stream>>>(img_out, img_target, out);
}